// Round 8
// baseline (326.626 us; speedup 1.0000x reference)
//
#include <hip/hip_runtime.h>
#include <stdint.h>
#include <string.h>

#define BB 256
#define TT 2048
#define DD 64
#define CC 128         // chunks per chain (was 64): 2x probe waves -> 4 waves/SIMD
#define SS 16          // steps per chunk (was 32); R1 precedent: SS=16 passes, absmax 64
#define C_L2E 1.44269504f
#define C_LN2 0.69314718f
// log2(1 + 2^-9): compensates bf16 truncation bias of the pack, folded into exp
#define C_BIAS 0.0028174f

typedef short sh8  __attribute__((ext_vector_type(8)));
typedef float f32x4 __attribute__((ext_vector_type(4)));

union BU { sh8 v8; unsigned int u[4]; unsigned short s[8]; };

__device__ __forceinline__ float expf_fast(float x) { return __builtin_amdgcn_exp2f(x * C_L2E); }
__device__ __forceinline__ unsigned short bf16rne(float x) {
    unsigned int u = __float_as_uint(x);
    u += 0x7FFF + ((u >> 16) & 1u);
    return (unsigned short)(u >> 16);
}
__device__ __forceinline__ unsigned int pkbf(float hi, float lo) {
    return __builtin_amdgcn_perm(__float_as_uint(hi), __float_as_uint(lo), 0x07060302u);
}

#define DPPMAX(x, ctrl, rm, bm) { int _xi = __float_as_int(x);                              \
    int _yi = __builtin_amdgcn_update_dpp(_xi, _xi, ctrl, rm, bm, false);                   \
    x = fmaxf(x, __int_as_float(_yi)); }

// ---------- kernel 0: lengths from mask only (verified R4-R7) ----------
__global__ __launch_bounds__(256) void crf_len(
    const int* __restrict__ mask, int* __restrict__ wsL)
{
    __shared__ int r4[4];
    const int c = blockIdx.x, tid = threadIdx.x;
    const int4* mrow = (const int4*)(mask + (size_t)c * TT);
    int4 a = mrow[tid * 2], b = mrow[tid * 2 + 1];
    int s = a.x + a.y + a.z + a.w + b.x + b.y + b.z + b.w;
#pragma unroll
    for (int xm = 32; xm >= 1; xm >>= 1) s += __shfl_xor(s, xm, 64);
    if ((tid & 63) == 0) r4[tid >> 6] = s;
    __syncthreads();
    if (tid == 0) wsL[c] = TT - (r4[0] + r4[1] + r4[2] + r4[3]);   // prefix mask: L = #zeros
}

// ---------- kernel 1a: label extraction, pure TLP streaming over y (verified R7) ----------
// 64 tokens/block, 16 lanes/token, ONE int4 per (lane,k), k=0..3 independent (16 payload
// VGPRs -> loads pipeline). Label = one-hot dot <y_row, index>, 4 narrow shfls. u8 out.
__global__ __launch_bounds__(256) void crf_lab(
    const int* __restrict__ y, unsigned char* __restrict__ labsG)
{
    const int tid = threadIdx.x;
    const int g = tid & 15, sub = tid >> 4;              // sub 0..15
    const size_t base = (size_t)blockIdx.x * 64;         // first token of block
    int4 v[4];
#pragma unroll
    for (int k = 0; k < 4; ++k)
        v[k] = ((const int4*)y)[(base + (size_t)k * 16 + sub) * 16 + g];  // 1 KB/wave/k
#pragma unroll
    for (int k = 0; k < 4; ++k) {
        int s = v[k].x * (4 * g) + v[k].y * (4 * g + 1)
              + v[k].z * (4 * g + 2) + v[k].w * (4 * g + 3);
#pragma unroll
        for (int xm = 1; xm <= 8; xm <<= 1) s += __shfl_xor(s, xm, 16);
        if (g == 0) labsG[base + k * 16 + sub] = (unsigned char)s;
    }
}

// ---------- kernel 1b: score gather (after probe: p is L3-resident; verified R7) ----------
__global__ __launch_bounds__(256) void crf_gth(
    const float* __restrict__ p, const unsigned char* __restrict__ labsG,
    const int* __restrict__ mask, const float* __restrict__ tr,
    float* __restrict__ wsS)
{
    __shared__ float redf[4];
    const int c = blockIdx.y, t0 = blockIdx.x * 256;
    const int tid = threadIdx.x;
    const size_t cb = (size_t)c * TT;
    const int tt = t0 + tid;

    const int m0 = mask[cb + tt];
    const int m1 = (tt + 1 < TT) ? mask[cb + tt + 1] : 1;
    const int l0 = labsG[cb + tt];

    float s = 0.f;
    if (m0 == 0)                                  // emission for valid token
        s += p[(cb + tt) * DD + l0];
    if (m1 == 0) {                                // pair (t,t+1) valid
        const int l1 = labsG[cb + tt + 1];
        s += tr[l0 * DD + l1];
    }
#pragma unroll
    for (int xm = 32; xm >= 1; xm >>= 1) s += __shfl_xor(s, xm, 64);
    if ((tid & 63) == 0) redf[tid >> 6] = s;
    __syncthreads();
    if (tid == 0)
        atomicAdd(&wsS[c], redf[0] + redf[1] + redf[2] + redf[3]);
}

// ---------- kernel 2: rank-1 chunk probes (VERBATIM verified R0 body; SS=16) ----------
// Block: 4 waves = (ic0,fwd),(ic0,bwd),(ic1,fwd),(ic1,bwd) — same p slab for L2 reuse.
// Wave batches 16 chains (c = 16cg+ml). Per step: 8 MFMA 16x16x32 bf16; state f32[16]/lane,
// lambda-relabelled (lam = 32kt2+16h+4q+r) so D -> next-B is in-lane. Per-chain freeze for
// padding; wave-uniform pow-2 renorm every 4 steps with per-chain sig. Probes stored bf16.
// CC=128 doubles wave count: 4096 waves = 16/CU = 4 waves/SIMD (VGPR ~128 permits 4) --
// double the latency hiding of the verified 2/SIMD config, body unchanged.
__global__ __launch_bounds__(256) void crf_probe(
    const float* __restrict__ p, const float* __restrict__ tr,
    const int* __restrict__ wsL,
    unsigned short* __restrict__ wsA, unsigned short* __restrict__ wsB, int* __restrict__ wsSig)
{
    const int tid = threadIdx.x, w = tid >> 6, lane = tid & 63;
    const int q = lane >> 4, ml = lane & 15;
    const int cg = blockIdx.x;
    const int ic = blockIdx.y * 2 + (w >> 1);
    const int bwd = w & 1;
    const int c = cg * 16 + ml;
    const int Lml = wsL[c];
    const int t0 = ic * SS, t1 = t0 + SS;
    const int ts = (ic == 0) ? 1 : t0;
    const float* prow = p + (size_t)c * TT * DD;

    // A fragments: fwd A = W^T (exp(T[lam][row])), bwd A = W (exp(T[row][lam]))
    BU A[4][2];
#pragma unroll
    for (int mt = 0; mt < 4; ++mt)
#pragma unroll
        for (int kt2 = 0; kt2 < 2; ++kt2)
#pragma unroll
            for (int j = 0; j < 8; ++j) {
                int lam = 32 * kt2 + 16 * (j >> 2) + 4 * q + (j & 3);
                float tv = bwd ? tr[(16 * mt + ml) * DD + lam] : tr[lam * DD + 16 * mt + ml];
                A[mt][kt2].s[j] = (short)bf16rne(expf_fast(tv));
            }

    // state xs[idx], idx = kt2*8 + h*4 + r  <->  lam = 32kt2+16h+4q+r
    float xs[16];
    if (!bwd && ic == 0) {           // exact start: u0 = exp(p[c,0,:])
#pragma unroll
        for (int k = 0; k < 4; ++k) {
            f32x4 v = *(const f32x4*)(prow + 16 * k + 4 * q);
#pragma unroll
            for (int r = 0; r < 4; ++r)
                xs[(k >> 1) * 8 + (k & 1) * 4 + r] = __builtin_amdgcn_exp2f(fmaf(v[r], C_L2E, C_BIAS));
        }
    } else {
#pragma unroll
        for (int i = 0; i < 16; ++i) xs[i] = 1.0f;
    }

    // wave max of L -> skip all-frozen step ranges
    int mL = Lml;
#pragma unroll
    for (int xm = 32; xm >= 1; xm >>= 1) { int o = __shfl_xor(mL, xm, 64); mL = o > mL ? o : mL; }
    int ibeg = 0, iend = SS;
    if (!bwd) { int ir = mL - t0; if (ir < 0) ir = 0; iend = (ir + 3) & ~3; if (iend > SS) iend = SS; }
    else      { int ir = t1 - mL; if (ir < 0) ir = 0; ibeg = ir & ~3; if (ibeg > SS) ibeg = SS; }

    int sig = 0;
    const f32x4 z4 = {0.f, 0.f, 0.f, 0.f};

    if (ibeg < iend) {
        f32x4 er[4][4];
#pragma unroll
        for (int s = 0; s < 4; ++s) {
            int i = ibeg + s;
            int t = bwd ? (t1 - 1 - i) : (t0 + i);
#pragma unroll
            for (int k = 0; k < 4; ++k)
                er[s][k] = *(const f32x4*)(prow + (size_t)t * DD + 16 * k + 4 * q);
        }
        for (int ib = ibeg; ib < iend; ib += 4) {
#pragma unroll
            for (int s = 0; s < 4; ++s) {
                const int i = ib + s;
                const int t = bwd ? (t1 - 1 - i) : (t0 + i);
                const bool act = (t >= ts) && (t < Lml);
                float ee[4][4];
#pragma unroll
                for (int k = 0; k < 4; ++k)
#pragma unroll
                    for (int r = 0; r < 4; ++r)
                        ee[k][r] = __builtin_amdgcn_exp2f(fmaf(er[s][k][r], C_L2E, C_BIAS));
                {   // prefetch step i+4 into slot s
                    int ipf = i + 4;
                    int tpf = bwd ? (t1 - 1 - ipf) : (t0 + ipf);
                    if (tpf < t0) tpf = t0;
                    if (tpf > t1 - 1) tpf = t1 - 1;
#pragma unroll
                    for (int k = 0; k < 4; ++k)
                        er[s][k] = *(const f32x4*)(prow + (size_t)tpf * DD + 16 * k + 4 * q);
                }
                float cand[16];
                BU Bf[2];
                f32x4 acc[4];
                if (!bwd) {     // u' = diag(e) W^T u : scale on output
#pragma unroll
                    for (int kt2 = 0; kt2 < 2; ++kt2)
#pragma unroll
                        for (int jj = 0; jj < 4; ++jj)
                            Bf[kt2].u[jj] = pkbf(xs[kt2 * 8 + 2 * jj + 1], xs[kt2 * 8 + 2 * jj]);
#pragma unroll
                    for (int mt = 0; mt < 4; ++mt) {
                        acc[mt] = __builtin_amdgcn_mfma_f32_16x16x32_bf16(A[mt][0].v8, Bf[0].v8, z4, 0, 0, 0);
                        acc[mt] = __builtin_amdgcn_mfma_f32_16x16x32_bf16(A[mt][1].v8, Bf[1].v8, acc[mt], 0, 0, 0);
                    }
#pragma unroll
                    for (int mt = 0; mt < 4; ++mt)
#pragma unroll
                        for (int r = 0; r < 4; ++r)
                            cand[(mt >> 1) * 8 + (mt & 1) * 4 + r] = acc[mt][r] * ee[mt][r];
                } else {        // w' = W (e .* w) : scale on input
                    float xsc[16];
#pragma unroll
                    for (int kt2 = 0; kt2 < 2; ++kt2)
#pragma unroll
                        for (int h = 0; h < 2; ++h)
#pragma unroll
                            for (int r = 0; r < 4; ++r)
                                xsc[kt2 * 8 + h * 4 + r] = xs[kt2 * 8 + h * 4 + r] * ee[2 * kt2 + h][r];
#pragma unroll
                    for (int kt2 = 0; kt2 < 2; ++kt2)
#pragma unroll
                        for (int jj = 0; jj < 4; ++jj)
                            Bf[kt2].u[jj] = pkbf(xsc[kt2 * 8 + 2 * jj + 1], xsc[kt2 * 8 + 2 * jj]);
#pragma unroll
                    for (int mt = 0; mt < 4; ++mt) {
                        acc[mt] = __builtin_amdgcn_mfma_f32_16x16x32_bf16(A[mt][0].v8, Bf[0].v8, z4, 0, 0, 0);
                        acc[mt] = __builtin_amdgcn_mfma_f32_16x16x32_bf16(A[mt][1].v8, Bf[1].v8, acc[mt], 0, 0, 0);
                    }
#pragma unroll
                    for (int mt = 0; mt < 4; ++mt)
#pragma unroll
                        for (int r = 0; r < 4; ++r)
                            cand[(mt >> 1) * 8 + (mt & 1) * 4 + r] = acc[mt][r];
                }
                if (s == 3) {   // wave-uniform pow-2 renorm, per-chain sig
                    float mx = fabsf(cand[0]);
#pragma unroll
                    for (int i2 = 1; i2 < 16; ++i2) mx = fmaxf(mx, fabsf(cand[i2]));
                    DPPMAX(mx, 0x111, 0xF, 0xF); DPPMAX(mx, 0x112, 0xF, 0xF);
                    DPPMAX(mx, 0x114, 0xF, 0xF); DPPMAX(mx, 0x118, 0xF, 0xF);
                    DPPMAX(mx, 0x142, 0xA, 0xF); DPPMAX(mx, 0x143, 0xC, 0xF);
                    int smx = __builtin_amdgcn_readlane(__float_as_int(mx), 63);
                    int kk = ((smx >> 23) & 255) - 127;
                    kk = kk < -124 ? -124 : (kk > 124 ? 124 : kk);
                    float sc = __int_as_float((unsigned)(127 - kk) << 23);
#pragma unroll
                    for (int i2 = 0; i2 < 16; ++i2) cand[i2] *= sc;
                    if (act) sig += kk;
                }
#pragma unroll
                for (int i2 = 0; i2 < 16; ++i2) xs[i2] = act ? cand[i2] : xs[i2];
            }
        }
    }

    unsigned short* dst = (bwd ? wsB : wsA) + ((size_t)c * CC + ic) * 64;
#pragma unroll
    for (int kt2 = 0; kt2 < 2; ++kt2)
#pragma unroll
        for (int h = 0; h < 2; ++h)
#pragma unroll
            for (int r = 0; r < 4; ++r)
                dst[32 * kt2 + 16 * h + 4 * q + r] = bf16rne(xs[kt2 * 8 + h * 4 + r]);
    if (!bwd && q == 0) wsSig[c * CC + ic] = sig;
}

// ---------- kernel 3: parallel rank-1 combine, one block per chain (CC=128) ----------
// logZ/ln2 = sig_0 + sum_{i>=1} [sig_i + log2(b_i.a_{i-1}) - log2(b_i.1)] + log2(1.a_{C-1})
__global__ __launch_bounds__(256) void crf_combine(
    const unsigned short* __restrict__ wsA, const unsigned short* __restrict__ wsB,
    const int* __restrict__ wsSig, const float* __restrict__ wsS,
    float* __restrict__ out)
{
    __shared__ float eParts[4];
    const int tid = threadIdx.x, w = tid >> 6, lane = tid & 63;
    const int c = blockIdx.x;

    float Ep = 0.f;
#pragma unroll 4
    for (int k = 0; k < CC / 4; ++k) {
        const int i = w * (CC / 4) + k;
        if (i == 0) continue;
        float b  = __uint_as_float((unsigned)wsB[((size_t)c * CC + i) * 64 + lane] << 16);
        float ap = __uint_as_float((unsigned)wsA[((size_t)c * CC + i - 1) * 64 + lane] << 16);
        float d1 = b * ap, d0 = b;
#pragma unroll
        for (int xm = 32; xm >= 1; xm >>= 1) { d1 += __shfl_xor(d1, xm, 64); d0 += __shfl_xor(d0, xm, 64); }
        Ep += (float)wsSig[c * CC + i] + __builtin_amdgcn_logf(d1) - __builtin_amdgcn_logf(d0);
    }
    if (w == 0) Ep += (float)wsSig[c * CC];
    if (w == 3) {
        float al = __uint_as_float((unsigned)wsA[((size_t)c * CC + CC - 1) * 64 + lane] << 16);
#pragma unroll
        for (int xm = 32; xm >= 1; xm >>= 1) al += __shfl_xor(al, xm, 64);
        Ep += __builtin_amdgcn_logf(al);
    }
    if (lane == 0) eParts[w] = Ep;
    __syncthreads();
    if (tid == 0) {
        float E = eParts[0] + eParts[1] + eParts[2] + eParts[3];
        out[c] = C_LN2 * E - wsS[c];
    }
}

extern "C" void kernel_launch(void* const* d_in, const int* in_sizes, int n_in,
                              void* d_out, int out_size, void* d_ws, size_t ws_size,
                              hipStream_t stream) {
    const float* p  = (const float*)d_in[0];
    const int*   y  = (const int*)d_in[1];
    const int*   mk = (const int*)d_in[2];
    const float* tr = (const float*)d_in[3];
    float* out = (float*)d_out;

    float* wsS  = (float*)d_ws;                                          // 1 KB @ 0
    int*   wsL  = (int*)((char*)d_ws + 1024);                            // 1 KB @ 1024
    int*   wsSg = (int*)((char*)d_ws + 4096);                            // 128 KB @ 4 KB (BB*CC*4)
    unsigned char* wsLb = (unsigned char*)((char*)d_ws + 262144);        // 512 KB @ 256 KB
    unsigned short* wsA = (unsigned short*)((char*)d_ws + (1u << 20));   // 4 MB @ 1 MB (bf16)
    unsigned short* wsB = (unsigned short*)((char*)d_ws + (5u << 20));   // 4 MB @ 5 MB

    hipMemsetAsync(d_ws, 0, 1024, stream);                               // zero wsS only
    crf_len<<<dim3(BB), dim3(256), 0, stream>>>(mk, wsL);
    crf_lab<<<dim3(BB * TT / 64), dim3(256), 0, stream>>>(y, wsLb);
    crf_probe<<<dim3(16, CC / 2), dim3(256), 0, stream>>>(p, tr, wsL, wsA, wsB, wsSg);
    crf_gth<<<dim3(8, BB), dim3(256), 0, stream>>>(p, wsLb, mk, tr, wsS);
    crf_combine<<<dim3(BB), dim3(256), 0, stream>>>(wsA, wsB, wsSg, wsS, out);
}

// Round 9
// 312.166 us; speedup vs baseline: 1.0463x; 1.0463x over previous
//
#include <hip/hip_runtime.h>
#include <stdint.h>
#include <string.h>

#define BB 256
#define TT 2048
#define DD 64
#define CC 64          // chunks per chain (R7 best config)
#define SS 32          // steps per chunk
#define C_L2E 1.44269504f
#define C_LN2 0.69314718f
// log2(1 + 2^-9): compensates bf16 truncation bias of the pack, folded into exp
#define C_BIAS 0.0028174f

typedef short sh8  __attribute__((ext_vector_type(8)));
typedef float f32x4 __attribute__((ext_vector_type(4)));

union BU { sh8 v8; unsigned int u[4]; unsigned short s[8]; };

__device__ __forceinline__ float expf_fast(float x) { return __builtin_amdgcn_exp2f(x * C_L2E); }
__device__ __forceinline__ unsigned short bf16rne(float x) {
    unsigned int u = __float_as_uint(x);
    u += 0x7FFF + ((u >> 16) & 1u);
    return (unsigned short)(u >> 16);
}
__device__ __forceinline__ unsigned int pkbf(float hi, float lo) {
    return __builtin_amdgcn_perm(__float_as_uint(hi), __float_as_uint(lo), 0x07060302u);
}

#define DPPMAX(x, ctrl, rm, bm) { int _xi = __float_as_int(x);                              \
    int _yi = __builtin_amdgcn_update_dpp(_xi, _xi, ctrl, rm, bm, false);                   \
    x = fmaxf(x, __int_as_float(_yi)); }

// ---------- kernel 0: lengths from mask only (verified R4-R8) ----------
__global__ __launch_bounds__(256) void crf_len(
    const int* __restrict__ mask, int* __restrict__ wsL)
{
    __shared__ int r4[4];
    const int c = blockIdx.x, tid = threadIdx.x;
    const int4* mrow = (const int4*)(mask + (size_t)c * TT);
    int4 a = mrow[tid * 2], b = mrow[tid * 2 + 1];
    int s = a.x + a.y + a.z + a.w + b.x + b.y + b.z + b.w;
#pragma unroll
    for (int xm = 32; xm >= 1; xm >>= 1) s += __shfl_xor(s, xm, 64);
    if ((tid & 63) == 0) r4[tid >> 6] = s;
    __syncthreads();
    if (tid == 0) wsL[c] = TT - (r4[0] + r4[1] + r4[2] + r4[3]);   // prefix mask: L = #zeros
}

// ---------- kernel 1a: label extraction, pure TLP streaming over y (verified R7) ----------
// 64 tokens/block, 16 lanes/token, ONE int4 per (lane,k), k=0..3 independent (16 payload
// VGPRs -> loads pipeline; R6 evidence: deeper arrays get re-serialized). Label =
// one-hot dot <y_row, index>, 4 narrow shfls. u8 out.
__global__ __launch_bounds__(256) void crf_lab(
    const int* __restrict__ y, unsigned char* __restrict__ labsG)
{
    const int tid = threadIdx.x;
    const int g = tid & 15, sub = tid >> 4;              // sub 0..15
    const size_t base = (size_t)blockIdx.x * 64;         // first token of block
    int4 v[4];
#pragma unroll
    for (int k = 0; k < 4; ++k)
        v[k] = ((const int4*)y)[(base + (size_t)k * 16 + sub) * 16 + g];  // 1 KB/wave/k
#pragma unroll
    for (int k = 0; k < 4; ++k) {
        int s = v[k].x * (4 * g) + v[k].y * (4 * g + 1)
              + v[k].z * (4 * g + 2) + v[k].w * (4 * g + 3);
#pragma unroll
        for (int xm = 1; xm <= 8; xm <<= 1) s += __shfl_xor(s, xm, 16);
        if (g == 0) labsG[base + k * 16 + sub] = (unsigned char)s;
    }
}

// ---------- kernel 1b: score gather (after probe: p is L3-resident; verified R7) ----------
__global__ __launch_bounds__(256) void crf_gth(
    const float* __restrict__ p, const unsigned char* __restrict__ labsG,
    const int* __restrict__ mask, const float* __restrict__ tr,
    float* __restrict__ wsS)
{
    __shared__ float redf[4];
    const int c = blockIdx.y, t0 = blockIdx.x * 256;
    const int tid = threadIdx.x;
    const size_t cb = (size_t)c * TT;
    const int tt = t0 + tid;

    const int m0 = mask[cb + tt];
    const int m1 = (tt + 1 < TT) ? mask[cb + tt + 1] : 1;
    const int l0 = labsG[cb + tt];

    float s = 0.f;
    if (m0 == 0)                                  // emission for valid token
        s += p[(cb + tt) * DD + l0];
    if (m1 == 0) {                                // pair (t,t+1) valid
        const int l1 = labsG[cb + tt + 1];
        s += tr[l0 * DD + l1];
    }
#pragma unroll
    for (int xm = 32; xm >= 1; xm >>= 1) s += __shfl_xor(s, xm, 64);
    if ((tid & 63) == 0) redf[tid >> 6] = s;
    __syncthreads();
    if (tid == 0)
        atomicAdd(&wsS[c], redf[0] + redf[1] + redf[2] + redf[3]);
}

// ---------- kernel 2: rank-1 chunk probes (R0 math; prefetch depth 4 -> 2) ----------
// Block: 4 waves = (ic0,fwd),(ic0,bwd),(ic1,fwd),(ic1,bwd) — same p slab for L2 reuse.
// Wave batches 16 chains (c = 16cg+ml). Per step: 8 MFMA 16x16x32 bf16; state f32[16]/lane,
// lambda-relabelled (lam = 32kt2+16h+4q+r); per-chain freeze; pow-2 renorm every 4 steps.
// R8 PMC: depth-4 er[4][4] (64 VGPR, kernel at 96) gets re-serialized by the allocator to
// <1 outstanding load/wave -> 1.4 TB/s latency-bound. Depth-2 er[2][4] (32 VGPR) matches
// the batch size the compiler provably pipelines in this session (crf_lab). Slots indexed
// statically (s&1) to avoid scratch (runtime-indexed ext_vector arrays -> local mem).
__global__ __launch_bounds__(256) void crf_probe(
    const float* __restrict__ p, const float* __restrict__ tr,
    const int* __restrict__ wsL,
    unsigned short* __restrict__ wsA, unsigned short* __restrict__ wsB, int* __restrict__ wsSig)
{
    const int tid = threadIdx.x, w = tid >> 6, lane = tid & 63;
    const int q = lane >> 4, ml = lane & 15;
    const int cg = blockIdx.x;
    const int ic = blockIdx.y * 2 + (w >> 1);
    const int bwd = w & 1;
    const int c = cg * 16 + ml;
    const int Lml = wsL[c];
    const int t0 = ic * SS, t1 = t0 + SS;
    const int ts = (ic == 0) ? 1 : t0;
    const float* prow = p + (size_t)c * TT * DD;

    // A fragments: fwd A = W^T (exp(T[lam][row])), bwd A = W (exp(T[row][lam]))
    BU A[4][2];
#pragma unroll
    for (int mt = 0; mt < 4; ++mt)
#pragma unroll
        for (int kt2 = 0; kt2 < 2; ++kt2)
#pragma unroll
            for (int j = 0; j < 8; ++j) {
                int lam = 32 * kt2 + 16 * (j >> 2) + 4 * q + (j & 3);
                float tv = bwd ? tr[(16 * mt + ml) * DD + lam] : tr[lam * DD + 16 * mt + ml];
                A[mt][kt2].s[j] = (short)bf16rne(expf_fast(tv));
            }

    // state xs[idx], idx = kt2*8 + h*4 + r  <->  lam = 32kt2+16h+4q+r
    float xs[16];
    if (!bwd && ic == 0) {           // exact start: u0 = exp(p[c,0,:])
#pragma unroll
        for (int k = 0; k < 4; ++k) {
            f32x4 v = *(const f32x4*)(prow + 16 * k + 4 * q);
#pragma unroll
            for (int r = 0; r < 4; ++r)
                xs[(k >> 1) * 8 + (k & 1) * 4 + r] = __builtin_amdgcn_exp2f(fmaf(v[r], C_L2E, C_BIAS));
        }
    } else {
#pragma unroll
        for (int i = 0; i < 16; ++i) xs[i] = 1.0f;
    }

    // wave max of L -> skip all-frozen step ranges
    int mL = Lml;
#pragma unroll
    for (int xm = 32; xm >= 1; xm >>= 1) { int o = __shfl_xor(mL, xm, 64); mL = o > mL ? o : mL; }
    int ibeg = 0, iend = SS;
    if (!bwd) { int ir = mL - t0; if (ir < 0) ir = 0; iend = (ir + 3) & ~3; if (iend > SS) iend = SS; }
    else      { int ir = t1 - mL; if (ir < 0) ir = 0; ibeg = ir & ~3; if (ibeg > SS) ibeg = SS; }

    int sig = 0;
    const f32x4 z4 = {0.f, 0.f, 0.f, 0.f};

    if (ibeg < iend) {
        f32x4 er[2][4];
#pragma unroll
        for (int s = 0; s < 2; ++s) {                 // preload steps ibeg, ibeg+1
            int i = ibeg + s;
            int t = bwd ? (t1 - 1 - i) : (t0 + i);
#pragma unroll
            for (int k = 0; k < 4; ++k)
                er[s][k] = *(const f32x4*)(prow + (size_t)t * DD + 16 * k + 4 * q);
        }
        for (int ib = ibeg; ib < iend; ib += 4) {
#pragma unroll
            for (int s = 0; s < 4; ++s) {             // static s -> slot s&1 static
                const int i = ib + s;
                const int t = bwd ? (t1 - 1 - i) : (t0 + i);
                const bool act = (t >= ts) && (t < Lml);
                float ee[4][4];
#pragma unroll
                for (int k = 0; k < 4; ++k)
#pragma unroll
                    for (int r = 0; r < 4; ++r)
                        ee[k][r] = __builtin_amdgcn_exp2f(fmaf(er[s & 1][k][r], C_L2E, C_BIAS));
                {   // prefetch step i+2 into slot s&1
                    int ipf = i + 2;
                    int tpf = bwd ? (t1 - 1 - ipf) : (t0 + ipf);
                    if (tpf < t0) tpf = t0;
                    if (tpf > t1 - 1) tpf = t1 - 1;
#pragma unroll
                    for (int k = 0; k < 4; ++k)
                        er[s & 1][k] = *(const f32x4*)(prow + (size_t)tpf * DD + 16 * k + 4 * q);
                }
                float cand[16];
                BU Bf[2];
                f32x4 acc[4];
                if (!bwd) {     // u' = diag(e) W^T u : scale on output
#pragma unroll
                    for (int kt2 = 0; kt2 < 2; ++kt2)
#pragma unroll
                        for (int jj = 0; jj < 4; ++jj)
                            Bf[kt2].u[jj] = pkbf(xs[kt2 * 8 + 2 * jj + 1], xs[kt2 * 8 + 2 * jj]);
#pragma unroll
                    for (int mt = 0; mt < 4; ++mt) {
                        acc[mt] = __builtin_amdgcn_mfma_f32_16x16x32_bf16(A[mt][0].v8, Bf[0].v8, z4, 0, 0, 0);
                        acc[mt] = __builtin_amdgcn_mfma_f32_16x16x32_bf16(A[mt][1].v8, Bf[1].v8, acc[mt], 0, 0, 0);
                    }
#pragma unroll
                    for (int mt = 0; mt < 4; ++mt)
#pragma unroll
                        for (int r = 0; r < 4; ++r)
                            cand[(mt >> 1) * 8 + (mt & 1) * 4 + r] = acc[mt][r] * ee[mt][r];
                } else {        // w' = W (e .* w) : scale on input
                    float xsc[16];
#pragma unroll
                    for (int kt2 = 0; kt2 < 2; ++kt2)
#pragma unroll
                        for (int h = 0; h < 2; ++h)
#pragma unroll
                            for (int r = 0; r < 4; ++r)
                                xsc[kt2 * 8 + h * 4 + r] = xs[kt2 * 8 + h * 4 + r] * ee[2 * kt2 + h][r];
#pragma unroll
                    for (int kt2 = 0; kt2 < 2; ++kt2)
#pragma unroll
                        for (int jj = 0; jj < 4; ++jj)
                            Bf[kt2].u[jj] = pkbf(xsc[kt2 * 8 + 2 * jj + 1], xsc[kt2 * 8 + 2 * jj]);
#pragma unroll
                    for (int mt = 0; mt < 4; ++mt) {
                        acc[mt] = __builtin_amdgcn_mfma_f32_16x16x32_bf16(A[mt][0].v8, Bf[0].v8, z4, 0, 0, 0);
                        acc[mt] = __builtin_amdgcn_mfma_f32_16x16x32_bf16(A[mt][1].v8, Bf[1].v8, acc[mt], 0, 0, 0);
                    }
#pragma unroll
                    for (int mt = 0; mt < 4; ++mt)
#pragma unroll
                        for (int r = 0; r < 4; ++r)
                            cand[(mt >> 1) * 8 + (mt & 1) * 4 + r] = acc[mt][r];
                }
                if (s == 3) {   // wave-uniform pow-2 renorm, per-chain sig
                    float mx = fabsf(cand[0]);
#pragma unroll
                    for (int i2 = 1; i2 < 16; ++i2) mx = fmaxf(mx, fabsf(cand[i2]));
                    DPPMAX(mx, 0x111, 0xF, 0xF); DPPMAX(mx, 0x112, 0xF, 0xF);
                    DPPMAX(mx, 0x114, 0xF, 0xF); DPPMAX(mx, 0x118, 0xF, 0xF);
                    DPPMAX(mx, 0x142, 0xA, 0xF); DPPMAX(mx, 0x143, 0xC, 0xF);
                    int smx = __builtin_amdgcn_readlane(__float_as_int(mx), 63);
                    int kk = ((smx >> 23) & 255) - 127;
                    kk = kk < -124 ? -124 : (kk > 124 ? 124 : kk);
                    float sc = __int_as_float((unsigned)(127 - kk) << 23);
#pragma unroll
                    for (int i2 = 0; i2 < 16; ++i2) cand[i2] *= sc;
                    if (act) sig += kk;
                }
#pragma unroll
                for (int i2 = 0; i2 < 16; ++i2) xs[i2] = act ? cand[i2] : xs[i2];
            }
        }
    }

    unsigned short* dst = (bwd ? wsB : wsA) + ((size_t)c * CC + ic) * 64;
#pragma unroll
    for (int kt2 = 0; kt2 < 2; ++kt2)
#pragma unroll
        for (int h = 0; h < 2; ++h)
#pragma unroll
            for (int r = 0; r < 4; ++r)
                dst[32 * kt2 + 16 * h + 4 * q + r] = bf16rne(xs[kt2 * 8 + h * 4 + r]);
    if (!bwd && q == 0) wsSig[c * CC + ic] = sig;
}

// ---------- kernel 3: parallel rank-1 combine, one block per chain ----------
// logZ/ln2 = sig_0 + sum_{i>=1} [sig_i + log2(b_i.a_{i-1}) - log2(b_i.1)] + log2(1.a_{C-1})
__global__ __launch_bounds__(256) void crf_combine(
    const unsigned short* __restrict__ wsA, const unsigned short* __restrict__ wsB,
    const int* __restrict__ wsSig, const float* __restrict__ wsS,
    float* __restrict__ out)
{
    __shared__ float eParts[4];
    const int tid = threadIdx.x, w = tid >> 6, lane = tid & 63;
    const int c = blockIdx.x;

    float Ep = 0.f;
#pragma unroll
    for (int k = 0; k < 16; ++k) {
        const int i = w * 16 + k;
        if (i == 0) continue;
        float b  = __uint_as_float((unsigned)wsB[((size_t)c * CC + i) * 64 + lane] << 16);
        float ap = __uint_as_float((unsigned)wsA[((size_t)c * CC + i - 1) * 64 + lane] << 16);
        float d1 = b * ap, d0 = b;
#pragma unroll
        for (int xm = 32; xm >= 1; xm >>= 1) { d1 += __shfl_xor(d1, xm, 64); d0 += __shfl_xor(d0, xm, 64); }
        Ep += (float)wsSig[c * CC + i] + __builtin_amdgcn_logf(d1) - __builtin_amdgcn_logf(d0);
    }
    if (w == 0) Ep += (float)wsSig[c * CC];
    if (w == 3) {
        float al = __uint_as_float((unsigned)wsA[((size_t)c * CC + CC - 1) * 64 + lane] << 16);
#pragma unroll
        for (int xm = 32; xm >= 1; xm >>= 1) al += __shfl_xor(al, xm, 64);
        Ep += __builtin_amdgcn_logf(al);
    }
    if (lane == 0) eParts[w] = Ep;
    __syncthreads();
    if (tid == 0) {
        float E = eParts[0] + eParts[1] + eParts[2] + eParts[3];
        out[c] = C_LN2 * E - wsS[c];
    }
}

extern "C" void kernel_launch(void* const* d_in, const int* in_sizes, int n_in,
                              void* d_out, int out_size, void* d_ws, size_t ws_size,
                              hipStream_t stream) {
    const float* p  = (const float*)d_in[0];
    const int*   y  = (const int*)d_in[1];
    const int*   mk = (const int*)d_in[2];
    const float* tr = (const float*)d_in[3];
    float* out = (float*)d_out;

    float* wsS  = (float*)d_ws;                                          // 1 KB @ 0
    int*   wsL  = (int*)((char*)d_ws + 1024);                            // 1 KB @ 1024
    int*   wsSg = (int*)((char*)d_ws + 4096);                            // 64 KB @ 4 KB
    unsigned char* wsLb = (unsigned char*)((char*)d_ws + 131072);        // 512 KB @ 128 KB
    unsigned short* wsA = (unsigned short*)((char*)d_ws + (1u << 20));   // 2 MB @ 1 MB (bf16)
    unsigned short* wsB = (unsigned short*)((char*)d_ws + (3u << 20));   // 2 MB @ 3 MB

    hipMemsetAsync(d_ws, 0, 1024, stream);                               // zero wsS only
    crf_len<<<dim3(BB), dim3(256), 0, stream>>>(mk, wsL);
    crf_lab<<<dim3(BB * TT / 64), dim3(256), 0, stream>>>(y, wsLb);
    crf_probe<<<dim3(16, CC / 2), dim3(256), 0, stream>>>(p, tr, wsL, wsA, wsB, wsSg);
    crf_gth<<<dim3(8, BB), dim3(256), 0, stream>>>(p, wsLb, mk, tr, wsS);
    crf_combine<<<dim3(BB), dim3(256), 0, stream>>>(wsA, wsB, wsSg, wsS, out);
}